// Round 2
// 558.325 us; speedup vs baseline: 1.0257x; 1.0257x over previous
//
#include <hip/hip_runtime.h>
#include <stdint.h>

#define TT   500
#define BB   64
#define IND  256
#define HD   512
#define OD   35
#define ROWS (TT*BB)   // 32000

typedef __attribute__((ext_vector_type(4))) int i32x4;

// fp32 scale exactly as numpy computes it
#define SCALE_F ((float)((1.0 - 0.001) / 31.0))

__device__ __forceinline__ void load16_lds(const int8_t* g, int8_t* l) {
  __builtin_amdgcn_global_load_lds((const __attribute__((address_space(1))) void*)g,
                                   (__attribute__((address_space(3))) void*)l, 16, 0, 0);
}

// ---------------------------------------------------------------- prep weights
// quant levels 0..31 as int8 (integer-exact GEMM operand)
__global__ __launch_bounds__(256) void k_prep(const float* __restrict__ W1,
                                              const float* __restrict__ W2,
                                              const float* __restrict__ W3,
                                              const float* __restrict__ W4,
                                              int8_t* __restrict__ wk1,
                                              int8_t* __restrict__ wk2,
                                              int8_t* __restrict__ wk3,
                                              int8_t* __restrict__ wk4) {
  int id = blockIdx.x * 256 + threadIdx.x;
  const float* W; int8_t* wk; int idx, K, H;
  if (id < 131072)       { idx = id;          W = W1; wk = wk1; K = 256; H = 512; }
  else if (id < 393216)  { idx = id - 131072; W = W2; wk = wk2; K = 512; H = 512; }
  else if (id < 655360)  { idx = id - 393216; W = W3; wk = wk3; K = 512; H = 512; }
  else                   { idx = id - 655360; W = W4; wk = wk4; K = 512; H = 35;  }
  int h = idx / K;
  int k = idx - h * K;
  int8_t bits = 0;
  if (h < H) {
    float w  = W[h * K + k];
    float wc = fminf(1.0f, fmaxf(0.001f, w));
    float v  = (wc - 0.001f) / SCALE_F;
    float q  = rintf(v);                 // round-half-even, matches np.round; 0..31
    bits = (int8_t)q;                    // exact small int
  }
  wk[idx] = bits;
}

// ---------------------------------------------------------------- cochlea scan
// 64-thread blocks, 4 blocks per batch element -> spreads over all 256 CUs.
__global__ __launch_bounds__(64) void k_cochlea(const float* __restrict__ x,
                                                const float* __restrict__ Wch,
                                                const float* __restrict__ cbetas,
                                                int8_t* __restrict__ chs,
                                                int* __restrict__ n_ch) {
  __shared__ float xs[TT];
  int b = blockIdx.x >> 2;
  int i = (blockIdx.x & 3) * 64 + threadIdx.x;
  for (int t = threadIdx.x; t < TT; t += 64) xs[t] = x[b * TT + t];
  __syncthreads();
  float w    = Wch[i];
  float beta = fminf(1.0f, fmaxf(0.0f, cbetas[i]));
  float mem  = 0.0f;
  for (int t = 0; t < TT; ++t) {
    float cur = __fmul_rn(xs[t], w);
    int   rs  = (mem > 1.0f);
    float t2  = __fadd_rn(__fmul_rn(beta, mem), cur);
    mem = rs ? __fsub_rn(t2, 1.0f) : t2;
    int spk = (mem > 1.0f);
    int row = t * BB + b;
    chs[(size_t)row * IND + i] = (int8_t)spk;
    unsigned long long bal = __ballot(spk);
    if (threadIdx.x == 0) atomicAdd(n_ch + row, (int)__popcll(bal));
  }
}

// ---------------------------------------------------------------- LDS MFMA GEMM (i8)
// m97-style: 128x128 block tile (4 waves, 64x64 each), BK=128 i8 bytes,
// global_load_lds width-16 staging with XOR bank swizzle (slot = chunk ^ (row&7)).
// Exact integer i8 GEMM, i32 accum (spikes 0/1 x levels 0..31, max 512*31 < 2^16).
// Byte-level addressing identical to the verified bf16 version (128-B rows, 8 chunks).
// A:[ROWS][KB], B:[128*coltiles][KB] row-major, KB = K elements = K bytes.
template<int KB>
__global__ __launch_bounds__(256) void k_gemm_lds(const int8_t* __restrict__ A,
                                                  const int8_t* __restrict__ B,
                                                  uint16_t* __restrict__ M,
                                                  int Hp, int coltiles) {
  __shared__ __align__(16) int8_t As[128 * 128];   // [row][slot*16..], row stride 128 B
  __shared__ __align__(16) int8_t Bs[128 * 128];
  int tid  = threadIdx.x;
  int lane = tid & 63, w = tid >> 6;
  int rt = blockIdx.x / coltiles, ct = blockIdx.x - rt * coltiles;
  int r0 = rt * 128, c0 = ct * 128;
  int wr = (w >> 1) * 64, wc = (w & 1) * 64;   // wave's 64x64 subtile
  int lr = lane & 15, kgf = lane >> 4;
  i32x4 acc[4][4];
#pragma unroll
  for (int i = 0; i < 4; ++i)
#pragma unroll
    for (int j = 0; j < 4; ++j) acc[i][j] = (i32x4){0, 0, 0, 0};

  for (int k0 = 0; k0 < KB; k0 += 128) {
    __syncthreads();   // previous iter's ds_reads complete before overwrite
#pragma unroll
    for (int i = 0; i < 4; ++i) {
      int L = i * 256 + tid;          // 16-B chunk index; wave covers 64 consecutive
      int row = L >> 3, c = L & 7;
      int kg = c ^ (row & 7);         // slot c stores global chunk kg
      load16_lds(A + (size_t)(r0 + row) * KB + k0 + kg * 16,
                 &As[(i * 256 + w * 64) * 16]);
    }
#pragma unroll
    for (int i = 0; i < 4; ++i) {
      int L = i * 256 + tid;
      int row = L >> 3, c = L & 7;
      int kg = c ^ (row & 7);
      load16_lds(B + (size_t)(c0 + row) * KB + k0 + kg * 16,
                 &Bs[(i * 256 + w * 64) * 16]);
    }
    __syncthreads();   // staged data visible (drains vmcnt)
#pragma unroll
    for (int kk = 0; kk < 2; ++kk) {
      i32x4 a[4], b[4];
#pragma unroll
      for (int s = 0; s < 4; ++s) {
        int arow = wr + s * 16 + lr;
        int sa   = (kk * 4 + kgf) ^ (arow & 7);
        a[s] = *(const i32x4*)&As[arow * 128 + sa * 16];
        int brow = wc + s * 16 + lr;
        int sb   = (kk * 4 + kgf) ^ (brow & 7);
        b[s] = *(const i32x4*)&Bs[brow * 128 + sb * 16];
      }
#pragma unroll
      for (int ar = 0; ar < 4; ++ar)
#pragma unroll
        for (int cs = 0; cs < 4; ++cs)
          acc[ar][cs] = __builtin_amdgcn_mfma_i32_16x16x64_i8(a[ar], b[cs], acc[ar][cs], 0, 0, 0);
    }
  }
  // C/D layout: col = lane&15, row = (lane>>4)*4 + reg (dtype-independent)
  int oc = lane & 15;
  int rb = (lane >> 4) * 4;
#pragma unroll
  for (int ar = 0; ar < 4; ++ar)
#pragma unroll
    for (int i = 0; i < 4; ++i) {
      size_t rowoff = (size_t)(r0 + wr + ar * 16 + rb + i) * Hp;
#pragma unroll
      for (int cs = 0; cs < 4; ++cs)
        M[rowoff + c0 + wc + cs * 16 + oc] = (uint16_t)acc[ar][cs][i];
    }
}

// ---------------------------------------------------------------- naive GEMM (layer 4, tiny, i8)
template<int KB>
__global__ __launch_bounds__(256) void k_gemm_naive(const int8_t* __restrict__ A,
                                                    const int8_t* __restrict__ B,
                                                    uint16_t* __restrict__ M,
                                                    int Hp, int coltiles) {
  int wid  = (blockIdx.x * 256 + threadIdx.x) >> 6;
  int lane = threadIdx.x & 63;
  int rt = wid / coltiles;
  int ct = wid - rt * coltiles;
  int r0 = rt * 64, c0 = ct * 64;
  int lr = lane & 15;
  int lk = (lane >> 4) * 16;           // byte offset of this lane's 16-B K-fragment
  const int8_t* ap = A + (size_t)(r0 + lr) * KB + lk;
  const int8_t* bp = B + (size_t)(c0 + lr) * KB + lk;
  i32x4 acc[4][4];
#pragma unroll
  for (int i = 0; i < 4; ++i)
#pragma unroll
    for (int j = 0; j < 4; ++j) acc[i][j] = (i32x4){0, 0, 0, 0};
#pragma unroll 2
  for (int k = 0; k < KB / 64; ++k) {
    i32x4 a[4], b[4];
#pragma unroll
    for (int s = 0; s < 4; ++s) {
      a[s] = *(const i32x4*)(ap + (size_t)s * 16 * KB + k * 64);
      b[s] = *(const i32x4*)(bp + (size_t)s * 16 * KB + k * 64);
    }
#pragma unroll
    for (int ar = 0; ar < 4; ++ar)
#pragma unroll
      for (int cs = 0; cs < 4; ++cs)
        acc[ar][cs] = __builtin_amdgcn_mfma_i32_16x16x64_i8(a[ar], b[cs], acc[ar][cs], 0, 0, 0);
  }
  int oc = lane & 15;
  int rb = (lane >> 4) * 4;
#pragma unroll
  for (int ar = 0; ar < 4; ++ar)
#pragma unroll
    for (int i = 0; i < 4; ++i) {
      size_t rowoff = (size_t)(r0 + ar * 16 + rb + i) * Hp;
#pragma unroll
      for (int cs = 0; cs < 4; ++cs)
        M[rowoff + c0 + cs * 16 + oc] = (uint16_t)acc[ar][cs][i];
    }
}

// ---------------------------------------------------------------- LIF scan
// 64-thread blocks; np-exact fp32 recurrence. Software-pipelined: prefetch the
// next UNR=10 (M,nrow) block while computing the current one so global-load
// latency hides under the serial mem chain. UB: H multiple of 64 -> b uniform
// per block (nrow loads scalarize).
template<int H, int Hp, bool WS, bool WM, bool WN, bool UB>
__global__ __launch_bounds__(64) void k_scan(const uint16_t* __restrict__ M,
                                             const int* __restrict__ nrow,
                                             const float* __restrict__ pbeta,
                                             float* __restrict__ spk_out,
                                             int8_t* __restrict__ s_out,
                                             int* __restrict__ n_out,
                                             float* __restrict__ mem_out) {
  int b, h;
  if constexpr (UB) {
    constexpr int BPB = H / 64;        // blocks per batch element
    b = blockIdx.x / BPB;
    h = (blockIdx.x % BPB) * 64 + threadIdx.x;
  } else {
    int t = blockIdx.x * 64 + threadIdx.x;
    if (t >= BB * H) return;
    b = t / H; h = t - b * H;
  }
  int tid = b * H + h;
  float beta = fminf(1.0f, fmaxf(0.0f, *pbeta));
  const double DSCALE = (double)SCALE_F;
  const double DWMIN  = (double)0.001f;
  float mem = 0.0f;
  uint16_t ma[10], mb2[10]; int na[10], nb2[10];

#define LOADBLK(mv, nv, T0)                                                  \
  { _Pragma("unroll") for (int j = 0; j < 10; ++j) {                         \
      int row = ((T0) + j) * BB + b;                                         \
      mv[j] = M[(size_t)row * Hp + h];                                       \
      nv[j] = nrow[row]; } }

#define STEPBLK(mv, nv, T0)                                                  \
  { _Pragma("unroll") for (int j = 0; j < 10; ++j) {                         \
      int t = (T0) + j; int row = t * BB + b;                                \
      float cur = (float)((double)mv[j] * DSCALE + (double)nv[j] * DWMIN);   \
      int   rs  = (mem > 1.0f);                                              \
      float t2  = __fadd_rn(__fmul_rn(beta, mem), cur);                      \
      mem = rs ? __fsub_rn(t2, 1.0f) : t2;                                   \
      int spk = (mem > 1.0f);                                                \
      spk_out[(size_t)t * (BB * H) + tid] = spk ? 1.0f : 0.0f;               \
      if (WS) s_out[(size_t)row * H + h] = (int8_t)spk;                      \
      if (WN) { unsigned long long bal = __ballot(spk);                      \
                if (threadIdx.x == 0) atomicAdd(n_out + row, (int)__popcll(bal)); } \
      if (WM) mem_out[(size_t)t * (BB * H) + tid] = mem; } }

  LOADBLK(ma, na, 0)
  for (int t0 = 0; t0 < TT; t0 += 20) {        // 500 = 25 * 20 exactly
    LOADBLK(mb2, nb2, t0 + 10)
    STEPBLK(ma, na, t0)
    if (t0 + 20 < TT) LOADBLK(ma, na, t0 + 20)
    STEPBLK(mb2, nb2, t0 + 10)
  }
#undef LOADBLK
#undef STEPBLK
}

// ---------------------------------------------------------------- launch
extern "C" void kernel_launch(void* const* d_in, const int* in_sizes, int n_in,
                              void* d_out, int out_size, void* d_ws, size_t ws_size,
                              hipStream_t stream) {
  const float* x      = (const float*)d_in[0];
  const float* Wch    = (const float*)d_in[1];
  const float* W1     = (const float*)d_in[2];
  const float* W2     = (const float*)d_in[3];
  const float* W3     = (const float*)d_in[4];
  const float* W4     = (const float*)d_in[5];
  const float* cbetas = (const float*)d_in[6];
  const float* b1     = (const float*)d_in[7];
  const float* b2     = (const float*)d_in[8];
  const float* b3     = (const float*)d_in[9];
  const float* b4     = (const float*)d_in[10];

  uint8_t* ws = (uint8_t*)d_ws;
  int8_t*   wk1  = (int8_t*)(ws + 0);          // 512*256   = 131072
  int8_t*   wk2  = (int8_t*)(ws + 131072);     // 512*512   = 262144
  int8_t*   wk3  = (int8_t*)(ws + 393216);     // 262144
  int8_t*   wk4  = (int8_t*)(ws + 655360);     // 64*512    = 32768
  int*      n_ch = (int*)(ws + 688128);        // 32000*4 each
  int*      n1   = (int*)(ws + 816128);
  int*      n2   = (int*)(ws + 944128);
  int*      n3   = (int*)(ws + 1072128);       // ends 1200128
  int8_t*   chs  = (int8_t*)(ws + 1200128);    // 32000*256 = 8192000
  int8_t*   sbuf = (int8_t*)(ws + 9392128);    // 32000*512 = 16384000
  uint16_t* mbuf = (uint16_t*)(ws + 25776128); // 32000*512*2 = 32768000 -> ends 58544128

  float* out  = (float*)d_out;
  float* spk1 = out;                // 500*64*512
  float* spk2 = out + 16384000;
  float* spk3 = out + 32768000;
  float* spk4 = out + 49152000;     // 500*64*35
  float* mem4 = out + 50272000;

  hipMemsetAsync(ws + 688128, 0, 512000, stream);

  k_prep<<<2688, 256, 0, stream>>>(W1, W2, W3, W4, wk1, wk2, wk3, wk4);
  k_cochlea<<<256, 64, 0, stream>>>(x, Wch, cbetas, chs, n_ch);

  // L1-3: 250 rowtiles x 4 coltiles = 1000 blocks of 128x128, i8 MFMA
  k_gemm_lds<256><<<1000, 256, 0, stream>>>(chs, wk1, mbuf, 512, 4);
  k_scan<512, 512, true, false, true, true><<<512, 64, 0, stream>>>(mbuf, n_ch, b1, spk1, sbuf, n1, nullptr);

  k_gemm_lds<512><<<1000, 256, 0, stream>>>(sbuf, wk2, mbuf, 512, 4);
  k_scan<512, 512, true, false, true, true><<<512, 64, 0, stream>>>(mbuf, n1, b2, spk2, sbuf, n2, nullptr);

  k_gemm_lds<512><<<1000, 256, 0, stream>>>(sbuf, wk3, mbuf, 512, 4);
  k_scan<512, 512, true, false, true, true><<<512, 64, 0, stream>>>(mbuf, n2, b3, spk3, sbuf, n3, nullptr);

  // layer 4: tiny (N=35 -> Hp=64), naive path: 500 waves = 125 blocks
  k_gemm_naive<512><<<125, 256, 0, stream>>>(sbuf, wk4, mbuf, 64, 1);
  k_scan<35, 64, false, true, false, false><<<35, 64, 0, stream>>>(mbuf, n3, b4, spk4, nullptr, nullptr, mem4);
}

// Round 3
// 520.671 us; speedup vs baseline: 1.0998x; 1.0723x over previous
//
#include <hip/hip_runtime.h>
#include <stdint.h>

#define TT   500
#define BB   64
#define IND  256
#define HD   512
#define OD   35
#define ROWS (TT*BB)   // 32000

typedef __attribute__((ext_vector_type(4))) int i32x4;

// fp32 scale exactly as numpy computes it
#define SCALE_F ((float)((1.0 - 0.001) / 31.0))

__device__ __forceinline__ void load16_lds(const int8_t* g, int8_t* l) {
  __builtin_amdgcn_global_load_lds((const __attribute__((address_space(1))) void*)g,
                                   (__attribute__((address_space(3))) void*)l, 16, 0, 0);
}

// ---------------------------------------------------------------- prep + cochlea (merged, independent work)
__global__ __launch_bounds__(256) void k_prep_cochlea(const float* __restrict__ W1,
                                                      const float* __restrict__ W2,
                                                      const float* __restrict__ W3,
                                                      const float* __restrict__ W4,
                                                      int8_t* __restrict__ wk1,
                                                      int8_t* __restrict__ wk2,
                                                      int8_t* __restrict__ wk3,
                                                      int8_t* __restrict__ wk4,
                                                      const float* __restrict__ x,
                                                      const float* __restrict__ Wch,
                                                      const float* __restrict__ cbetas,
                                                      int8_t* __restrict__ chs,
                                                      int* __restrict__ n_ch) {
  __shared__ float xs[TT];
  if (blockIdx.x < 2688) {
    // ---- weight quant: levels 0..31 as int8 (integer-exact GEMM operand)
    int id = blockIdx.x * 256 + threadIdx.x;
    const float* W; int8_t* wk; int idx, K, H;
    if (id < 131072)       { idx = id;          W = W1; wk = wk1; K = 256; H = 512; }
    else if (id < 393216)  { idx = id - 131072; W = W2; wk = wk2; K = 512; H = 512; }
    else if (id < 655360)  { idx = id - 393216; W = W3; wk = wk3; K = 512; H = 512; }
    else                   { idx = id - 655360; W = W4; wk = wk4; K = 512; H = 35;  }
    int h = idx / K;
    int k = idx - h * K;
    int8_t bits = 0;
    if (h < H) {
      float w  = W[h * K + k];
      float wc = fminf(1.0f, fmaxf(0.001f, w));
      float v  = (wc - 0.001f) / SCALE_F;
      float q  = rintf(v);                 // round-half-even, matches np.round; 0..31
      bits = (int8_t)q;                    // exact small int
    }
    wk[idx] = bits;
  } else {
    // ---- cochlea LIF scan: one block per batch element, 256 threads = 256 channels
    int b = blockIdx.x - 2688;
    int i = threadIdx.x;
    for (int t = threadIdx.x; t < TT; t += 256) xs[t] = x[b * TT + t];
    __syncthreads();
    float w    = Wch[i];
    float beta = fminf(1.0f, fmaxf(0.0f, cbetas[i]));
    float mem  = 0.0f;
    for (int t = 0; t < TT; ++t) {
      float cur = __fmul_rn(xs[t], w);
      int   rs  = (mem > 1.0f);
      float t2  = __fadd_rn(__fmul_rn(beta, mem), cur);
      mem = rs ? __fsub_rn(t2, 1.0f) : t2;
      int spk = (mem > 1.0f);
      int row = t * BB + b;
      chs[(size_t)row * IND + i] = (int8_t)spk;
      unsigned long long bal = __ballot(spk);
      if ((threadIdx.x & 63) == 0) atomicAdd(n_ch + row, (int)__popcll(bal));
    }
  }
}

// ---------------------------------------------------------------- LDS MFMA GEMM (i8)
// 128x128 block tile (4 waves, 64x64 each), BK=128 i8 bytes, global_load_lds
// width-16 staging with XOR bank swizzle (slot = chunk ^ (row&7)). Exact integer
// i8 GEMM, i32 accum. XCD-chunked blockIdx swizzle (grid%8==0 -> bijective) so
// the 4 coltile-blocks sharing A-rows land on one XCD (A reads become L2 hits).
// M stores are non-temporal (read-once by the scan, cross-XCD anyway).
template<int KB>
__global__ __launch_bounds__(256) void k_gemm_lds(const int8_t* __restrict__ A,
                                                  const int8_t* __restrict__ B,
                                                  uint16_t* __restrict__ M,
                                                  int Hp, int coltiles) {
  __shared__ __align__(16) int8_t As[128 * 128];   // [row][slot*16..], row stride 128 B
  __shared__ __align__(16) int8_t Bs[128 * 128];
  int tid  = threadIdx.x;
  int lane = tid & 63, w = tid >> 6;
  int nwg = gridDim.x;
  int bid = blockIdx.x;
  if (!(nwg & 7)) bid = (bid & 7) * (nwg >> 3) + (bid >> 3);   // XCD-chunked, bijective
  int rt = bid / coltiles, ct = bid - rt * coltiles;
  int r0 = rt * 128, c0 = ct * 128;
  int wr = (w >> 1) * 64, wc = (w & 1) * 64;   // wave's 64x64 subtile
  int lr = lane & 15, kgf = lane >> 4;
  i32x4 acc[4][4];
#pragma unroll
  for (int i = 0; i < 4; ++i)
#pragma unroll
    for (int j = 0; j < 4; ++j) acc[i][j] = (i32x4){0, 0, 0, 0};

  for (int k0 = 0; k0 < KB; k0 += 128) {
    __syncthreads();   // previous iter's ds_reads complete before overwrite
#pragma unroll
    for (int i = 0; i < 4; ++i) {
      int L = i * 256 + tid;          // 16-B chunk index; wave covers 64 consecutive
      int row = L >> 3, c = L & 7;
      int kg = c ^ (row & 7);         // slot c stores global chunk kg
      load16_lds(A + (size_t)(r0 + row) * KB + k0 + kg * 16,
                 &As[(i * 256 + w * 64) * 16]);
    }
#pragma unroll
    for (int i = 0; i < 4; ++i) {
      int L = i * 256 + tid;
      int row = L >> 3, c = L & 7;
      int kg = c ^ (row & 7);
      load16_lds(B + (size_t)(c0 + row) * KB + k0 + kg * 16,
                 &Bs[(i * 256 + w * 64) * 16]);
    }
    __syncthreads();   // staged data visible (drains vmcnt)
#pragma unroll
    for (int kk = 0; kk < 2; ++kk) {
      i32x4 a[4], b[4];
#pragma unroll
      for (int s = 0; s < 4; ++s) {
        int arow = wr + s * 16 + lr;
        int sa   = (kk * 4 + kgf) ^ (arow & 7);
        a[s] = *(const i32x4*)&As[arow * 128 + sa * 16];
        int brow = wc + s * 16 + lr;
        int sb   = (kk * 4 + kgf) ^ (brow & 7);
        b[s] = *(const i32x4*)&Bs[brow * 128 + sb * 16];
      }
#pragma unroll
      for (int ar = 0; ar < 4; ++ar)
#pragma unroll
        for (int cs = 0; cs < 4; ++cs)
          acc[ar][cs] = __builtin_amdgcn_mfma_i32_16x16x64_i8(a[ar], b[cs], acc[ar][cs], 0, 0, 0);
    }
  }
  // C/D layout: col = lane&15, row = (lane>>4)*4 + reg (dtype-independent)
  int oc = lane & 15;
  int rb = (lane >> 4) * 4;
#pragma unroll
  for (int ar = 0; ar < 4; ++ar)
#pragma unroll
    for (int i = 0; i < 4; ++i) {
      size_t rowoff = (size_t)(r0 + wr + ar * 16 + rb + i) * Hp;
#pragma unroll
      for (int cs = 0; cs < 4; ++cs)
        __builtin_nontemporal_store((uint16_t)acc[ar][cs][i],
                                    &M[rowoff + c0 + wc + cs * 16 + oc]);
    }
}

// ---------------------------------------------------------------- naive GEMM (layer 4, tiny, i8)
template<int KB>
__global__ __launch_bounds__(256) void k_gemm_naive(const int8_t* __restrict__ A,
                                                    const int8_t* __restrict__ B,
                                                    uint16_t* __restrict__ M,
                                                    int Hp, int coltiles) {
  int wid  = (blockIdx.x * 256 + threadIdx.x) >> 6;
  int lane = threadIdx.x & 63;
  int rt = wid / coltiles;
  int ct = wid - rt * coltiles;
  int r0 = rt * 64, c0 = ct * 64;
  int lr = lane & 15;
  int lk = (lane >> 4) * 16;           // byte offset of this lane's 16-B K-fragment
  const int8_t* ap = A + (size_t)(r0 + lr) * KB + lk;
  const int8_t* bp = B + (size_t)(c0 + lr) * KB + lk;
  i32x4 acc[4][4];
#pragma unroll
  for (int i = 0; i < 4; ++i)
#pragma unroll
    for (int j = 0; j < 4; ++j) acc[i][j] = (i32x4){0, 0, 0, 0};
#pragma unroll 2
  for (int k = 0; k < KB / 64; ++k) {
    i32x4 a[4], b[4];
#pragma unroll
    for (int s = 0; s < 4; ++s) {
      a[s] = *(const i32x4*)(ap + (size_t)s * 16 * KB + k * 64);
      b[s] = *(const i32x4*)(bp + (size_t)s * 16 * KB + k * 64);
    }
#pragma unroll
    for (int ar = 0; ar < 4; ++ar)
#pragma unroll
      for (int cs = 0; cs < 4; ++cs)
        acc[ar][cs] = __builtin_amdgcn_mfma_i32_16x16x64_i8(a[ar], b[cs], acc[ar][cs], 0, 0, 0);
  }
  int oc = lane & 15;
  int rb = (lane >> 4) * 4;
#pragma unroll
  for (int ar = 0; ar < 4; ++ar)
#pragma unroll
    for (int i = 0; i < 4; ++i) {
      size_t rowoff = (size_t)(r0 + ar * 16 + rb + i) * Hp;
#pragma unroll
      for (int cs = 0; cs < 4; ++cs)
        M[rowoff + c0 + cs * 16 + oc] = (uint16_t)acc[ar][cs][i];
    }
}

// ---------------------------------------------------------------- LIF scan
// 64-thread blocks; np-exact fp32 recurrence. 3-deep software pipeline: each
// 10-step block's (M,nrow) loads are issued 20 steps (~800 cy) before use, so
// LLC/HBM latency is fully hidden (the old 2-buffer version stalled every other
// block). NT loads for read-once mbuf, NT stores for write-once float outputs
// (keeps sbuf/chs L2-resident for the next GEMM's A reads).
template<int H, int Hp, bool WS, bool WM, bool WN, bool UB>
__global__ __launch_bounds__(64) void k_scan(const uint16_t* __restrict__ M,
                                             const int* __restrict__ nrow,
                                             const float* __restrict__ pbeta,
                                             float* __restrict__ spk_out,
                                             int8_t* __restrict__ s_out,
                                             int* __restrict__ n_out,
                                             float* __restrict__ mem_out) {
  int b, h;
  if constexpr (UB) {
    constexpr int BPB = H / 64;        // blocks per batch element
    b = blockIdx.x / BPB;
    h = (blockIdx.x % BPB) * 64 + threadIdx.x;
  } else {
    int t = blockIdx.x * 64 + threadIdx.x;
    if (t >= BB * H) return;
    b = t / H; h = t - b * H;
  }
  int tid = b * H + h;
  float beta = fminf(1.0f, fmaxf(0.0f, *pbeta));
  const double DSCALE = (double)SCALE_F;
  const double DWMIN  = (double)0.001f;
  float mem = 0.0f;
  const uint16_t* Mp = M + (size_t)b * Hp + h;   // + t*(BB*Hp)
  const int*      np = nrow + b;                 // + t*BB
  uint16_t mA[10], mB[10], mC[10]; int nA[10], nB[10], nC[10];

#define LOADBLK(mv, nv, G)                                                   \
  { int T0 = (G) * 10;                                                       \
    _Pragma("unroll") for (int j = 0; j < 10; ++j) {                         \
      mv[j] = __builtin_nontemporal_load(Mp + (size_t)(T0 + j) * (BB * Hp)); \
      nv[j] = np[(T0 + j) * BB]; } }

#define STEPBLK(mv, nv, G)                                                   \
  { int T0 = (G) * 10;                                                       \
    _Pragma("unroll") for (int j = 0; j < 10; ++j) {                         \
      int t = T0 + j; int row = t * BB + b;                                  \
      float cur = (float)((double)mv[j] * DSCALE + (double)nv[j] * DWMIN);   \
      int   rs  = (mem > 1.0f);                                              \
      float t2  = __fadd_rn(__fmul_rn(beta, mem), cur);                      \
      mem = rs ? __fsub_rn(t2, 1.0f) : t2;                                   \
      int spk = (mem > 1.0f);                                                \
      __builtin_nontemporal_store(spk ? 1.0f : 0.0f,                         \
                                  &spk_out[(size_t)t * (BB * H) + tid]);     \
      if (WS) s_out[(size_t)row * H + h] = (int8_t)spk;                      \
      if (WN) { unsigned long long bal = __ballot(spk);                      \
                if (threadIdx.x == 0) atomicAdd(n_out + row, (int)__popcll(bal)); } \
      if (WM) __builtin_nontemporal_store(mem,                               \
                                  &mem_out[(size_t)t * (BB * H) + tid]); } }

  LOADBLK(mA, nA, 0)
  LOADBLK(mB, nB, 1)
  for (int g = 0; g < 48; g += 3) {      // 50 blocks of 10: 16x3 + 2 epilogue
    LOADBLK(mC, nC, g + 2)
    STEPBLK(mA, nA, g)
    LOADBLK(mA, nA, g + 3)
    STEPBLK(mB, nB, g + 1)
    LOADBLK(mB, nB, g + 4)
    STEPBLK(mC, nC, g + 2)
  }
  STEPBLK(mA, nA, 48)
  STEPBLK(mB, nB, 49)
#undef LOADBLK
#undef STEPBLK
}

// ---------------------------------------------------------------- launch
extern "C" void kernel_launch(void* const* d_in, const int* in_sizes, int n_in,
                              void* d_out, int out_size, void* d_ws, size_t ws_size,
                              hipStream_t stream) {
  const float* x      = (const float*)d_in[0];
  const float* Wch    = (const float*)d_in[1];
  const float* W1     = (const float*)d_in[2];
  const float* W2     = (const float*)d_in[3];
  const float* W3     = (const float*)d_in[4];
  const float* W4     = (const float*)d_in[5];
  const float* cbetas = (const float*)d_in[6];
  const float* b1     = (const float*)d_in[7];
  const float* b2     = (const float*)d_in[8];
  const float* b3     = (const float*)d_in[9];
  const float* b4     = (const float*)d_in[10];

  uint8_t* ws = (uint8_t*)d_ws;
  int8_t*   wk1  = (int8_t*)(ws + 0);          // 512*256   = 131072
  int8_t*   wk2  = (int8_t*)(ws + 131072);     // 512*512   = 262144
  int8_t*   wk3  = (int8_t*)(ws + 393216);     // 262144
  int8_t*   wk4  = (int8_t*)(ws + 655360);     // 64*512    = 32768
  int*      n_ch = (int*)(ws + 688128);        // 32000*4 each
  int*      n1   = (int*)(ws + 816128);
  int*      n2   = (int*)(ws + 944128);
  int*      n3   = (int*)(ws + 1072128);       // ends 1200128
  int8_t*   chs  = (int8_t*)(ws + 1200128);    // 32000*256 = 8192000
  int8_t*   sbuf = (int8_t*)(ws + 9392128);    // 32000*512 = 16384000
  uint16_t* mbuf = (uint16_t*)(ws + 25776128); // 32000*512*2 = 32768000 -> ends 58544128

  float* out  = (float*)d_out;
  float* spk1 = out;                // 500*64*512
  float* spk2 = out + 16384000;
  float* spk3 = out + 32768000;
  float* spk4 = out + 49152000;     // 500*64*35
  float* mem4 = out + 50272000;

  hipMemsetAsync(ws + 688128, 0, 512000, stream);

  // prep (blocks 0..2687) + cochlea (blocks 2688..2751), independent work
  k_prep_cochlea<<<2752, 256, 0, stream>>>(W1, W2, W3, W4, wk1, wk2, wk3, wk4,
                                           x, Wch, cbetas, chs, n_ch);

  // L1-3: 250 rowtiles x 4 coltiles = 1000 blocks of 128x128, i8 MFMA
  k_gemm_lds<256><<<1000, 256, 0, stream>>>(chs, wk1, mbuf, 512, 4);
  k_scan<512, 512, true, false, true, true><<<512, 64, 0, stream>>>(mbuf, n_ch, b1, spk1, sbuf, n1, nullptr);

  k_gemm_lds<512><<<1000, 256, 0, stream>>>(sbuf, wk2, mbuf, 512, 4);
  k_scan<512, 512, true, false, true, true><<<512, 64, 0, stream>>>(mbuf, n1, b2, spk2, sbuf, n2, nullptr);

  k_gemm_lds<512><<<1000, 256, 0, stream>>>(sbuf, wk3, mbuf, 512, 4);
  k_scan<512, 512, true, false, true, true><<<512, 64, 0, stream>>>(mbuf, n2, b3, spk3, sbuf, n3, nullptr);

  // layer 4: tiny (N=35 -> Hp=64), naive path: 500 waves = 125 blocks
  k_gemm_naive<512><<<125, 256, 0, stream>>>(sbuf, wk4, mbuf, 64, 1);
  k_scan<35, 64, false, true, false, false><<<35, 64, 0, stream>>>(mbuf, n3, b4, spk4, nullptr, nullptr, mem4);
}